// Round 3
// baseline (2894.055 us; speedup 1.0000x reference)
//
#include <hip/hip_runtime.h>
#include <cfloat>

// Problem constants (B=16,S=4096,H=512,G=2,V=320,D=128)
#define M_TOTAL 65536
#define K_H     512
#define GD      256
#define NG      2
#define ND      128
#define NV      320

// d_out float offsets: quantized [16,4096,256], encodings [2,16,4096,320],
// distances [2,16,4096,320], perplexity scalar
#define Q_OFF     0
#define ENC_OFF   16777216
#define DIST_OFF  58720256
#define PERP_OFF  100663296

// ---- c2[g,v] = ||codevector||^2, precomputed into workspace ----
__global__ void c2_kernel(const float* __restrict__ C, float* __restrict__ c2out) {
  int gv = blockIdx.x * 64 + threadIdx.x;   // grid 10 x 64 = 640
  const float4* p = (const float4*)(C + (size_t)gv * ND);
  float s = 0.f;
#pragma unroll 8
  for (int q = 0; q < 32; ++q) {
    float4 v = p[q];
    s += v.x * v.x + v.y * v.y + v.z * v.z + v.w * v.w;
  }
  c2out[gv] = s;
}

// ---- fused: project -> distances -> argmin -> one-hot/hist/gather ----
// 64-row tile per block, 256 threads.
// LDS = hs 32 KB + shbuf 16 KB = 48 KB -> 3 blocks/CU (12 waves, 37.5% occ).
// Round-2 lesson: phase-2 MUST stage C through LDS. Global-C at 16 lanes x
// 8 KB stride generated ~10 GB of L2 requests; the 384 MB output write
// stream sweeps L2+L3 so C re-reads missed to HBM (1.35 GB fetch) and
// dirty-line churn amplified writes 7x (2.77 GB). Round-0 counterfactual
// with LDS-C: 140 MB fetch / 237 MB write.
// New vs round 0: T14 reg-staged double-buffer in BOTH phases (issue next
// tile's global loads before compute, ds_write after the barrier) so the
// staging latency is off the inter-barrier critical path; 3 blocks/CU
// instead of 2; encodings written in-kernel (no 168 MB memset).
__global__ __launch_bounds__(256, 3) void quant_main(
    const float* __restrict__ X,     // [65536,512]
    const float* __restrict__ W,     // [512,256]
    const float* __restrict__ bias,  // [256]
    const float* __restrict__ C,     // [2,320,128]
    const float* __restrict__ c2,    // ws: [2,320]
    int* __restrict__ hist,          // ws: [2,320]
    float* __restrict__ out) {
  // hs: h-tile [64][128] XOR-swizzled (32 KB)
  // shbuf (16 KB), time-shared: phase-1 staging As_T 16x68=1088 + Ws 16x160=2560
  //   = 3648 floats; phase-2 Cs chunk [32][128] = 4096 floats; idx share.
  __shared__ float hs[64 * 128];
  __shared__ float shbuf[4096];

  const int t   = threadIdx.x;
  const int tx  = t & 15;       // lane%16 within wave
  const int ty  = t >> 4;       // 0..15
  const int row0 = blockIdx.x * 64;

  float* out_q    = out + Q_OFF;
  float* out_enc  = out + ENC_OFF;
  float* out_dist = out + DIST_OFF;

  // fixed per-thread staging coordinates
  const int ar  = t >> 2, akq = t & 3;   // As: row ar, quad akq (16 floats/row/kc)
  const int wk0 = t >> 5, wc4 = t & 31;  // Ws: k wk0 & wk0+8, col-quad wc4
  const int cq  = t & 31, cv0 = t >> 5;  // Cs: quad cq, rows cv0+8*it

  for (int g = 0; g < NG; ++g) {
    // ================= phase 1: h_g tile = X[rows] @ W[:, g*128..] + b ======
    // K-step 16, 32 kc iterations; k summation order = ascending (bitwise
    // identical to previous rounds).
    float acc1[4][8];  // rows 4*ty+i, cols g*128 + 8*tx + j
#pragma unroll
    for (int i = 0; i < 4; ++i)
#pragma unroll
      for (int j = 0; j < 8; ++j) acc1[i][j] = 0.f;

    // T14 prologue: load+write kc=0 (shbuf dead here: first use for g=0;
    // post-gather barrier protects for g=1)
    float4 xr  = *(const float4*)(X + (size_t)(row0 + ar) * K_H + 4 * akq);
    float4 wr0 = *(const float4*)(W + (size_t)(wk0)     * GD + g * ND + 4 * wc4);
    float4 wr1 = *(const float4*)(W + (size_t)(wk0 + 8) * GD + g * ND + 4 * wc4);
    {
      shbuf[68 * (4 * akq + 0) + ar] = xr.x;
      shbuf[68 * (4 * akq + 1) + ar] = xr.y;
      shbuf[68 * (4 * akq + 2) + ar] = xr.z;
      shbuf[68 * (4 * akq + 3) + ar] = xr.w;
      int wb = 20 * (wc4 >> 2) + 4 * (wc4 & 3);
      *(float4*)&shbuf[1088 + 160 * wk0       + wb] = wr0;
      *(float4*)&shbuf[1088 + 160 * (wk0 + 8) + wb] = wr1;
    }

    for (int kc = 0; kc < 32; ++kc) {
      __syncthreads();            // stage kc visible to all waves
      if (kc < 31) {              // issue kc+1 loads; latency hides under compute
        xr  = *(const float4*)(X + (size_t)(row0 + ar) * K_H + (kc + 1) * 16 + 4 * akq);
        wr0 = *(const float4*)(W + (size_t)((kc + 1) * 16 + wk0)     * GD + g * ND + 4 * wc4);
        wr1 = *(const float4*)(W + (size_t)((kc + 1) * 16 + wk0 + 8) * GD + g * ND + 4 * wc4);
      }
#pragma unroll
      for (int k = 0; k < 16; ++k) {
        float4 a = *(const float4*)&shbuf[68 * k + 4 * ty];
        int wb = 1088 + 160 * k + 20 * (tx >> 1) + 8 * (tx & 1);
        float4 w0 = *(const float4*)&shbuf[wb];
        float4 w1 = *(const float4*)&shbuf[wb + 4];
        float av[4] = {a.x, a.y, a.z, a.w};
        float wv[8] = {w0.x, w0.y, w0.z, w0.w, w1.x, w1.y, w1.z, w1.w};
#pragma unroll
        for (int i = 0; i < 4; ++i)
#pragma unroll
          for (int j = 0; j < 8; ++j) acc1[i][j] += av[i] * wv[j];
      }
      __syncthreads();            // all waves done reading stage kc
      if (kc < 31) {
        shbuf[68 * (4 * akq + 0) + ar] = xr.x;
        shbuf[68 * (4 * akq + 1) + ar] = xr.y;
        shbuf[68 * (4 * akq + 2) + ar] = xr.z;
        shbuf[68 * (4 * akq + 3) + ar] = xr.w;
        int wb = 20 * (wc4 >> 2) + 4 * (wc4 & 3);
        *(float4*)&shbuf[1088 + 160 * wk0       + wb] = wr0;
        *(float4*)&shbuf[1088 + 160 * (wk0 + 8) + wb] = wr1;
      }
    }
    // bias
#pragma unroll
    for (int j = 0; j < 8; ++j) {
      float bj = bias[g * ND + 8 * tx + j];
#pragma unroll
      for (int i = 0; i < 4; ++i) acc1[i][j] += bj;
    }
    // write h tile to LDS, XOR-swizzled: hs[r][d] at 128*r + 4*((d>>2)^(r&7)) + (d&3)
#pragma unroll
    for (int i = 0; i < 4; ++i) {
      int r = 4 * ty + i, sw = r & 7;
      float4 v0 = make_float4(acc1[i][0], acc1[i][1], acc1[i][2], acc1[i][3]);
      float4 v1 = make_float4(acc1[i][4], acc1[i][5], acc1[i][6], acc1[i][7]);
      *(float4*)&hs[128 * r + 4 * ((2 * tx) ^ sw)]     = v0;
      *(float4*)&hs[128 * r + 4 * ((2 * tx + 1) ^ sw)] = v1;
    }
    __syncthreads();   // hs ready; also: all waves past phase-1 staging reads

    // h2 per row, kept in registers (shuffle-reduced across the 16 tx lanes)
    float h2r[4];
#pragma unroll
    for (int i = 0; i < 4; ++i) {
      int r = 4 * ty + i, sw = r & 7;
      float s = 0.f;
#pragma unroll
      for (int qq = 0; qq < 2; ++qq) {
        int q = tx + 16 * qq;
        float4 v = *(const float4*)&hs[128 * r + 4 * (q ^ sw)];
        s += v.x * v.x + v.y * v.y + v.z * v.z + v.w * v.w;
      }
#pragma unroll
      for (int off = 1; off < 16; off <<= 1) s += __shfl_xor(s, off);
      h2r[i] = s;
    }

    // ====== phase 2: distances + argmin over 10 LDS-staged V-chunks of 32 ===
    float runval[4]; int runidx[4];
#pragma unroll
    for (int i = 0; i < 4; ++i) { runval[i] = FLT_MAX; runidx[i] = 0; }

    // T14 prologue: stage chunk 0 (safe: all waves past hs-ready barrier)
    float4 cr[4];
#pragma unroll
    for (int it = 0; it < 4; ++it)
      cr[it] = *(const float4*)(C + (size_t)((g * NV + cv0 + 8 * it) * ND) + 4 * cq);
#pragma unroll
    for (int it = 0; it < 4; ++it) {
      int v = cv0 + 8 * it;
      *(float4*)&shbuf[128 * v + 4 * (cq ^ (v & 7))] = cr[it];
    }

    for (int vc = 0; vc < 10; ++vc) {
      __syncthreads();            // Cs[vc] visible
      if (vc < 9) {               // issue chunk vc+1 loads (hide under compute)
        int vb1 = 32 * (vc + 1);
#pragma unroll
        for (int it = 0; it < 4; ++it)
          cr[it] = *(const float4*)(C + (size_t)((g * NV + vb1 + cv0 + 8 * it) * ND) + 4 * cq);
      }
      float acc[4][2];
#pragma unroll
      for (int i = 0; i < 4; ++i) { acc[i][0] = 0.f; acc[i][1] = 0.f; }
#pragma unroll 4
      for (int q = 0; q < 32; ++q) {
        float4 a[4], b[2];
#pragma unroll
        for (int i = 0; i < 4; ++i) {
          int r = 4 * ty + i;
          a[i] = *(const float4*)&hs[128 * r + 4 * (q ^ (r & 7))];
        }
#pragma unroll
        for (int j = 0; j < 2; ++j) {
          int v = tx + 16 * j;
          b[j] = *(const float4*)&shbuf[128 * v + 4 * (q ^ (v & 7))];
        }
#pragma unroll
        for (int i = 0; i < 4; ++i)
#pragma unroll
          for (int j = 0; j < 2; ++j)
            acc[i][j] += a[i].x * b[j].x + a[i].y * b[j].y +
                         a[i].z * b[j].z + a[i].w * b[j].w;
      }
      int vb = 32 * vc;
      float c2v[2];
      c2v[0] = c2[g * NV + vb + tx];
      c2v[1] = c2[g * NV + vb + tx + 16];
#pragma unroll
      for (int i = 0; i < 4; ++i) {
        int rg = row0 + 4 * ty + i;
        size_t dbase = (size_t)(g * M_TOTAL + rg) * NV + vb;
#pragma unroll
        for (int j = 0; j < 2; ++j) {   // j ascending -> v ascending (argmin-first)
          float d = h2r[i] - 2.f * acc[i][j] + c2v[j];
          out_dist[dbase + tx + 16 * j] = d;
          int vidx = vb + tx + 16 * j;
          if (d < runval[i]) { runval[i] = d; runidx[i] = vidx; }
        }
      }
      __syncthreads();            // all waves done reading Cs[vc]
      if (vc < 9) {
#pragma unroll
        for (int it = 0; it < 4; ++it) {
          int v = cv0 + 8 * it;
          *(float4*)&shbuf[128 * v + 4 * (cq ^ (v & 7))] = cr[it];
        }
      }
    }

    // argmin reduce across the 16 tx lanes (tie -> lower index, like jnp.argmin)
    int fidx[4];
#pragma unroll
    for (int i = 0; i < 4; ++i) {
      float v = runval[i]; int idx = runidx[i];
#pragma unroll
      for (int off = 1; off < 16; off <<= 1) {
        float ov = __shfl_xor(v, off);
        int oi = __shfl_xor(idx, off);
        if (ov < v || (ov == v && oi < idx)) { v = ov; idx = oi; }
      }
      fidx[i] = idx;
      if (tx == 0) atomicAdd(&hist[g * NV + idx], 1);
    }

    // one-hot encodings written directly (replaces the 168 MB memset):
    // fidx[i] is uniform across the 16 tx lanes; each lane covers 5 quads.
#pragma unroll
    for (int i = 0; i < 4; ++i) {
      int rg = row0 + 4 * ty + i;
      float* rowp = out_enc + (size_t)(g * M_TOTAL + rg) * NV;
      int fi = fidx[i];
#pragma unroll
      for (int jj = 0; jj < 5; ++jj) {
        int q = tx + 16 * jj;     // 16 lanes -> 256 B contiguous per (i,jj)
        float4 e;
        e.x = (fi == 4 * q + 0) ? 1.f : 0.f;
        e.y = (fi == 4 * q + 1) ? 1.f : 0.f;
        e.z = (fi == 4 * q + 2) ? 1.f : 0.f;
        e.w = (fi == 4 * q + 3) ? 1.f : 0.f;
        *(float4*)(rowp + 4 * q) = e;
      }
    }

    // share idx via shbuf (Cs dead: all waves past the vc=9 trailing barrier)
    if (tx == 0) {
#pragma unroll
      for (int i = 0; i < 4; ++i) ((int*)shbuf)[4 * ty + i] = fidx[i];
    }
    __syncthreads();
    // cooperative quantized-feature gather (float4, coalesced)
#pragma unroll
    for (int it = 0; it < 8; ++it) {
      int flat = t + 256 * it;     // 0..2047: 64 rows x 32 quads
      int r = flat >> 5, q = flat & 31;
      int idx = ((int*)shbuf)[r];
      float4 cv = *(const float4*)(C + (size_t)((g * NV + idx) * ND) + 4 * q);
      *(float4*)(out_q + (size_t)(row0 + r) * GD + g * ND + 4 * q) = cv;
    }
    __syncthreads();   // protect next-g phase-1 prologue shbuf writes
  }
}

// ---- perplexity from histogram ----
__global__ void perp_kernel(const int* __restrict__ hist, float* __restrict__ outp) {
  int t = threadIdx.x;  // 64 threads = 1 wave
  float s0 = 0.f, s1 = 0.f;
  for (int v = t; v < NV; v += 64) {
    float p0 = fminf(fmaxf((float)hist[v] * (1.0f / 65536.f), 1e-10f), 1.0f);
    float p1 = fminf(fmaxf((float)hist[NV + v] * (1.0f / 65536.f), 1e-10f), 1.0f);
    s0 += p0 * logf(p0 + 1e-10f);
    s1 += p1 * logf(p1 + 1e-10f);
  }
#pragma unroll
  for (int off = 1; off < 64; off <<= 1) {
    s0 += __shfl_xor(s0, off);
    s1 += __shfl_xor(s1, off);
  }
  if (t == 0) outp[0] = 0.5f * (expf(-s0) + expf(-s1));
}

extern "C" void kernel_launch(void* const* d_in, const int* in_sizes, int n_in,
                              void* d_out, int out_size, void* d_ws, size_t ws_size,
                              hipStream_t stream) {
  const float* X    = (const float*)d_in[0];
  const float* W    = (const float*)d_in[1];
  const float* bias = (const float*)d_in[2];
  const float* C    = (const float*)d_in[3];
  float* out = (float*)d_out;

  int*   hist = (int*)d_ws;                 // [2,320] ints
  float* c2   = (float*)d_ws + 1024;        // [2,320] floats

  // only the histogram needs zeroing (encodings are fully written in-kernel)
  hipMemsetAsync(d_ws, 0, 4096, stream);

  c2_kernel<<<10, 64, 0, stream>>>(C, c2);
  quant_main<<<1024, 256, 0, stream>>>(X, W, bias, C, c2, hist, out);
  perp_kernel<<<1, 64, 0, stream>>>(hist, out + PERP_OFF);
}

// Round 4
// 1118.395 us; speedup vs baseline: 2.5877x; 2.5877x over previous
//
#include <hip/hip_runtime.h>
#include <cfloat>

// Problem constants (B=16,S=4096,H=512,G=2,V=320,D=128)
#define M_TOTAL 65536
#define K_H     512
#define GD      256
#define NG      2
#define ND      128
#define NV      320

// d_out float offsets: quantized [16,4096,256], encodings [2,16,4096,320],
// distances [2,16,4096,320], perplexity scalar
#define Q_OFF     0
#define ENC_OFF   16777216
#define DIST_OFF  58720256
#define PERP_OFF  100663296

// ---- c2[g,v] = ||codevector||^2, precomputed into workspace ----
__global__ void c2_kernel(const float* __restrict__ C, float* __restrict__ c2out) {
  int gv = blockIdx.x * 64 + threadIdx.x;   // grid 10 x 64 = 640
  const float4* p = (const float4*)(C + (size_t)gv * ND);
  float s = 0.f;
#pragma unroll 8
  for (int q = 0; q < 32; ++q) {
    float4 v = p[q];
    s += v.x * v.x + v.y * v.y + v.z * v.z + v.w * v.w;
  }
  c2out[gv] = s;
}

// ---- fused: project -> distances -> argmin -> one-hot/hist/gather ----
// 64-row tile per block, 256 threads, 64 KB LDS (2 blocks/CU).
// This is the round-0 proven-clean structure (785 us, 0.39 GB HBM traffic)
// with EXACTLY ONE change: full one-hot encoding rows are written in-kernel
// (full-line 256 B stores) so the 168 MB enc memset is eliminated.
// Lessons r1-r3: every restructure bundle (occupancy 3-4 blk/CU, global-C,
// K-step 8, T14 reg-prefetch double-buffer) blew L2-fabric traffic up to
// 4-10 GB (write amp 7-17x) and regressed 1.5-2.3x. Do not reintroduce
// without single-variable evidence.
__global__ __launch_bounds__(256, 2) void quant_main(
    const float* __restrict__ X,     // [65536,512]
    const float* __restrict__ W,     // [512,256]
    const float* __restrict__ bias,  // [256]
    const float* __restrict__ C,     // [2,320,128]
    const float* __restrict__ c2,    // ws: [2,320]
    int* __restrict__ hist,          // ws: [2,320]
    float* __restrict__ out) {
  // hs: h-tile [64][128] swizzled stride-128 (32 KB)
  // reg2: phase1 staging (As_T 1088 dw + Ws 2560 dw) OR Cs chunk [64][128] (32 KB)
  __shared__ float hs[64 * 128];
  __shared__ float reg2[8192];

  const int t   = threadIdx.x;
  const int tx  = t & 15;       // lane%16 within wave
  const int ty  = t >> 4;       // 0..15
  const int row0 = blockIdx.x * 64;

  float* out_q    = out + Q_OFF;
  float* out_enc  = out + ENC_OFF;
  float* out_dist = out + DIST_OFF;

  for (int g = 0; g < NG; ++g) {
    // ================= phase 1: h_g tile = X[rows] @ W[:, g*128..] + b ======
    float acc1[4][8];  // rows 4*ty+i, cols g*128 + 8*tx + j
#pragma unroll
    for (int i = 0; i < 4; ++i)
#pragma unroll
      for (int j = 0; j < 8; ++j) acc1[i][j] = 0.f;

    for (int kc = 0; kc < 32; ++kc) {
      __syncthreads();  // reg2 reuse barrier
      // As_T[k][r] at reg2[68*k + r], k=0..15, r=0..63
      {
        int r = t >> 2, kq = t & 3;
        float4 x4 = *(const float4*)(X + (size_t)(row0 + r) * K_H + kc * 16 + kq * 4);
        reg2[68 * (4 * kq + 0) + r] = x4.x;
        reg2[68 * (4 * kq + 1) + r] = x4.y;
        reg2[68 * (4 * kq + 2) + r] = x4.z;
        reg2[68 * (4 * kq + 3) + r] = x4.w;
      }
      // Ws[k][c] at reg2[1088 + 160*k + 20*(c>>4) + (c&15)], c = 0..127 (quad-padded)
#pragma unroll
      for (int i = 0; i < 2; ++i) {
        int fq = t + 256 * i;          // 0..511
        int k = fq >> 5, c4 = fq & 31;
        float4 w4 = *(const float4*)(W + (size_t)(kc * 16 + k) * GD + g * ND + 4 * c4);
        int c = 4 * c4;
        *(float4*)&reg2[1088 + 160 * k + 20 * (c >> 4) + (c & 15)] = w4;
      }
      __syncthreads();
#pragma unroll
      for (int k = 0; k < 16; ++k) {
        float4 a = *(const float4*)&reg2[68 * k + 4 * ty];
        int wb = 1088 + 160 * k + 20 * (tx >> 1) + 8 * (tx & 1);
        float4 w0 = *(const float4*)&reg2[wb];
        float4 w1 = *(const float4*)&reg2[wb + 4];
        float av[4] = {a.x, a.y, a.z, a.w};
        float wv[8] = {w0.x, w0.y, w0.z, w0.w, w1.x, w1.y, w1.z, w1.w};
#pragma unroll
        for (int i = 0; i < 4; ++i)
#pragma unroll
          for (int j = 0; j < 8; ++j) acc1[i][j] += av[i] * wv[j];
      }
    }
    // bias
#pragma unroll
    for (int j = 0; j < 8; ++j) {
      float bj = bias[g * ND + 8 * tx + j];
#pragma unroll
      for (int i = 0; i < 4; ++i) acc1[i][j] += bj;
    }
    // write h tile to LDS, XOR-swizzled: hs[r][d] at 128*r + 4*((d>>2)^(r&7)) + (d&3)
#pragma unroll
    for (int i = 0; i < 4; ++i) {
      int r = 4 * ty + i, sw = r & 7;
      float4 v0 = make_float4(acc1[i][0], acc1[i][1], acc1[i][2], acc1[i][3]);
      float4 v1 = make_float4(acc1[i][4], acc1[i][5], acc1[i][6], acc1[i][7]);
      *(float4*)&hs[128 * r + 4 * ((2 * tx) ^ sw)]     = v0;
      *(float4*)&hs[128 * r + 4 * ((2 * tx + 1) ^ sw)] = v1;
    }
    __syncthreads();

    // h2 per row, kept in registers (shuffle-reduced across the 16 tx lanes)
    float h2r[4];
#pragma unroll
    for (int i = 0; i < 4; ++i) {
      int r = 4 * ty + i, sw = r & 7;
      float s = 0.f;
#pragma unroll
      for (int qq = 0; qq < 2; ++qq) {
        int q = tx + 16 * qq;
        float4 v = *(const float4*)&hs[128 * r + 4 * (q ^ sw)];
        s += v.x * v.x + v.y * v.y + v.z * v.z + v.w * v.w;
      }
#pragma unroll
      for (int off = 1; off < 16; off <<= 1) s += __shfl_xor(s, off);
      h2r[i] = s;
    }

    // ================= phase 2: distances + argmin over 5 V-chunks of 64 ====
    float runval[4]; int runidx[4];
#pragma unroll
    for (int i = 0; i < 4; ++i) { runval[i] = FLT_MAX; runidx[i] = 0; }

    for (int vc = 0; vc < 5; ++vc) {
      int vbase = vc * 64;
      __syncthreads();
      // stage Cs chunk [64][128], swizzled like hs
#pragma unroll
      for (int i = 0; i < 8; ++i) {
        int fq = t + 256 * i;
        int v = fq >> 5, q = fq & 31;
        float4 cv = *(const float4*)(C + (size_t)((g * NV + vbase + v) * ND) + 4 * q);
        *(float4*)&reg2[128 * v + 4 * (q ^ (v & 7))] = cv;
      }
      __syncthreads();
      float acc[4][4];
#pragma unroll
      for (int i = 0; i < 4; ++i)
#pragma unroll
        for (int j = 0; j < 4; ++j) acc[i][j] = 0.f;
#pragma unroll 4
      for (int q = 0; q < 32; ++q) {
        float4 a[4], b[4];
#pragma unroll
        for (int i = 0; i < 4; ++i) {
          int r = 4 * ty + i;
          a[i] = *(const float4*)&hs[128 * r + 4 * (q ^ (r & 7))];
        }
#pragma unroll
        for (int j = 0; j < 4; ++j) {
          int v = tx + 16 * j;
          b[j] = *(const float4*)&reg2[128 * v + 4 * (q ^ (v & 7))];
        }
#pragma unroll
        for (int i = 0; i < 4; ++i)
#pragma unroll
          for (int j = 0; j < 4; ++j)
            acc[i][j] += a[i].x * b[j].x + a[i].y * b[j].y +
                         a[i].z * b[j].z + a[i].w * b[j].w;
      }
      float c2v[4];
#pragma unroll
      for (int j = 0; j < 4; ++j) c2v[j] = c2[g * NV + vbase + tx + 16 * j];
#pragma unroll
      for (int i = 0; i < 4; ++i) {
        int rg = row0 + 4 * ty + i;
        size_t dbase = (size_t)(g * M_TOTAL + rg) * NV + vbase;
#pragma unroll
        for (int j = 0; j < 4; ++j) {   // j ascending -> v ascending (argmin-first)
          float d = h2r[i] - 2.f * acc[i][j] + c2v[j];
          out_dist[dbase + tx + 16 * j] = d;
          int vidx = vbase + tx + 16 * j;
          if (d < runval[i]) { runval[i] = d; runidx[i] = vidx; }
        }
      }
    }

    // argmin reduce across the 16 tx lanes (tie -> lower index, like jnp.argmin)
    int fidx[4];
#pragma unroll
    for (int i = 0; i < 4; ++i) {
      float v = runval[i]; int idx = runidx[i];
#pragma unroll
      for (int off = 1; off < 16; off <<= 1) {
        float ov = __shfl_xor(v, off);
        int oi = __shfl_xor(idx, off);
        if (ov < v || (ov == v && oi < idx)) { v = ov; idx = oi; }
      }
      fidx[i] = idx;
      if (tx == 0) atomicAdd(&hist[g * NV + idx], 1);
    }

    // one-hot encodings written as full rows (the single change vs round 0:
    // replaces the 168 MB memset). fidx[i] is uniform across the 16 tx lanes;
    // per (i,jj) the 16 lanes store 256 B contiguous (full lines).
#pragma unroll
    for (int i = 0; i < 4; ++i) {
      int rg = row0 + 4 * ty + i;
      float* rowp = out_enc + (size_t)(g * M_TOTAL + rg) * NV;
      int fi = fidx[i];
#pragma unroll
      for (int jj = 0; jj < 5; ++jj) {
        int q = tx + 16 * jj;
        float4 e;
        e.x = (fi == 4 * q + 0) ? 1.f : 0.f;
        e.y = (fi == 4 * q + 1) ? 1.f : 0.f;
        e.z = (fi == 4 * q + 2) ? 1.f : 0.f;
        e.w = (fi == 4 * q + 3) ? 1.f : 0.f;
        *(float4*)(rowp + 4 * q) = e;
      }
    }

    __syncthreads();               // Cs region now dead for all waves
    if (tx == 0) {
#pragma unroll
      for (int i = 0; i < 4; ++i) ((int*)reg2)[4 * ty + i] = fidx[i];
    }
    __syncthreads();
    // cooperative quantized-feature gather (float4, coalesced)
#pragma unroll
    for (int it = 0; it < 8; ++it) {
      int flat = t + 256 * it;     // 0..2047: 64 rows x 32 quads
      int r = flat >> 5, q = flat & 31;
      int idx = ((int*)reg2)[r];
      float4 cv = *(const float4*)(C + (size_t)((g * NV + idx) * ND) + 4 * q);
      *(float4*)(out_q + (size_t)(row0 + r) * GD + g * ND + 4 * q) = cv;
    }
  }
}

// ---- perplexity from histogram ----
__global__ void perp_kernel(const int* __restrict__ hist, float* __restrict__ outp) {
  int t = threadIdx.x;  // 64 threads = 1 wave
  float s0 = 0.f, s1 = 0.f;
  for (int v = t; v < NV; v += 64) {
    float p0 = fminf(fmaxf((float)hist[v] * (1.0f / 65536.f), 1e-10f), 1.0f);
    float p1 = fminf(fmaxf((float)hist[NV + v] * (1.0f / 65536.f), 1e-10f), 1.0f);
    s0 += p0 * logf(p0 + 1e-10f);
    s1 += p1 * logf(p1 + 1e-10f);
  }
#pragma unroll
  for (int off = 1; off < 64; off <<= 1) {
    s0 += __shfl_xor(s0, off);
    s1 += __shfl_xor(s1, off);
  }
  if (t == 0) outp[0] = 0.5f * (expf(-s0) + expf(-s1));
}

extern "C" void kernel_launch(void* const* d_in, const int* in_sizes, int n_in,
                              void* d_out, int out_size, void* d_ws, size_t ws_size,
                              hipStream_t stream) {
  const float* X    = (const float*)d_in[0];
  const float* W    = (const float*)d_in[1];
  const float* bias = (const float*)d_in[2];
  const float* C    = (const float*)d_in[3];
  float* out = (float*)d_out;

  int*   hist = (int*)d_ws;                 // [2,320] ints
  float* c2   = (float*)d_ws + 1024;        // [2,320] floats

  // only the histogram needs zeroing (encodings fully written in-kernel)
  hipMemsetAsync(d_ws, 0, 4096, stream);

  c2_kernel<<<10, 64, 0, stream>>>(C, c2);
  quant_main<<<1024, 256, 0, stream>>>(X, W, bias, C, c2, hist, out);
  perp_kernel<<<1, 64, 0, stream>>>(hist, out + PERP_OFF);
}